// Round 1
// baseline (803.160 us; speedup 1.0000x reference)
//
#include <hip/hip_runtime.h>
#include <math.h>

#define BB 64
#define SS 500
#define DIN 64
#define DD 128
#define HH 8
#define HDIM 16
#define HALF_ 5
#define WINW 11
#define LL 2
#define FF 512
#define MM (BB*SS)          // 32000 rows
#define LN_EPS 1e-12f

// ---------------------------------------------------------------------------
// Embedding: h = LN(x @ W_in + b_in + pos_emb[2+s] + tt_emb)
// one block per row, 128 threads (one per output dim)
// ---------------------------------------------------------------------------
__global__ __launch_bounds__(128) void k_embed(
    const float* __restrict__ x, const float* __restrict__ Win,
    const float* __restrict__ bin, const float* __restrict__ pos,
    const float* __restrict__ tt, const float* __restrict__ g,
    const float* __restrict__ be, float* __restrict__ h)
{
    const int row = blockIdx.x;       // 0..MM-1
    const int d   = threadIdx.x;      // 0..127
    const int s   = row % SS;

    __shared__ float xs[DIN];
    if (d < DIN) xs[d] = x[(size_t)row * DIN + d];
    __syncthreads();

    float acc = bin[d];
    #pragma unroll 8
    for (int i = 0; i < DIN; ++i) acc += xs[i] * Win[i * DD + d];
    acc += pos[(size_t)(2 + s) * DD + d] + tt[d];

    // LayerNorm over 128 (2 waves)
    float s1 = acc, s2 = acc * acc;
    #pragma unroll
    for (int off = 1; off < 64; off <<= 1) {
        s1 += __shfl_xor(s1, off);
        s2 += __shfl_xor(s2, off);
    }
    __shared__ float rs[2][2];
    const int wid = d >> 6;
    if ((d & 63) == 0) { rs[wid][0] = s1; rs[wid][1] = s2; }
    __syncthreads();
    const float S1 = rs[0][0] + rs[1][0];
    const float S2 = rs[0][1] + rs[1][1];
    const float mean = S1 * (1.0f / DD);
    const float var  = S2 * (1.0f / DD) - mean * mean;
    const float rstd = rsqrtf(var + LN_EPS);
    h[(size_t)row * DD + d] = (acc - mean) * rstd * g[d] + be[d];
}

// ---------------------------------------------------------------------------
// Generic fp32 GEMM tile kernel: C[M x ncols] slice = A[M x K] @ W[K x ldw]
// block tile: 64 rows x 128 cols, 256 threads, per-thread 4m x 8n.
// EPI: 0 = bias+store, 1 = bias+gelu(exact)+store, 2 = bias+residual+LN+store
// ---------------------------------------------------------------------------
template<int EPI>
__global__ __launch_bounds__(256) void k_gemm(
    const float* __restrict__ A, int lda, int K,
    const float* __restrict__ W, int ldw,
    const float* __restrict__ bias,
    const float* __restrict__ res,
    const float* __restrict__ g, const float* __restrict__ bt,
    float* __restrict__ C, int ldc)
{
    __shared__ float As[64][132];     // padded: float4 reads stay aligned, 2-way banks
    __shared__ float Ws[128][128];

    const int tid = threadIdx.x;
    const int tn = tid & 15;          // 0..15 -> col groups 4tn and 64+4tn
    const int tm = tid >> 4;          // 0..15 -> rows tm*4 .. tm*4+3
    const int m0 = blockIdx.x * 64;
    const int n0 = blockIdx.y * 128;

    float acc[4][8];
    #pragma unroll
    for (int j = 0; j < 4; ++j)
        #pragma unroll
        for (int i = 0; i < 8; ++i) acc[j][i] = 0.f;

    for (int k0 = 0; k0 < K; k0 += 128) {
        // stage A tile 64x128
        #pragma unroll
        for (int it = 0; it < 8; ++it) {
            int lin = tid * 4 + it * 1024;
            int r = lin >> 7, c = lin & 127;
            float4 av = *(const float4*)(A + (size_t)(m0 + r) * lda + k0 + c);
            *(float4*)&As[r][c] = av;
        }
        // stage W tile 128x128
        #pragma unroll
        for (int it = 0; it < 16; ++it) {
            int lin = tid * 4 + it * 1024;
            int r = lin >> 7, c = lin & 127;
            float4 wv = *(const float4*)(W + (size_t)(k0 + r) * ldw + n0 + c);
            *(float4*)&Ws[r][c] = wv;
        }
        __syncthreads();

        #pragma unroll 2
        for (int kk = 0; kk < 128; kk += 4) {
            float4 a4[4];
            #pragma unroll
            for (int j = 0; j < 4; ++j)
                a4[j] = *(const float4*)&As[tm * 4 + j][kk];
            #pragma unroll
            for (int t = 0; t < 4; ++t) {
                float4 wlo = *(const float4*)&Ws[kk + t][tn * 4];
                float4 whi = *(const float4*)&Ws[kk + t][64 + tn * 4];
                #pragma unroll
                for (int j = 0; j < 4; ++j) {
                    float av = ((const float*)&a4[j])[t];
                    acc[j][0] += av * wlo.x; acc[j][1] += av * wlo.y;
                    acc[j][2] += av * wlo.z; acc[j][3] += av * wlo.w;
                    acc[j][4] += av * whi.x; acc[j][5] += av * whi.y;
                    acc[j][6] += av * whi.z; acc[j][7] += av * whi.w;
                }
            }
        }
        __syncthreads();
    }

    // epilogue
    #pragma unroll
    for (int j = 0; j < 4; ++j) {
        const int row = m0 + tm * 4 + j;
        if constexpr (EPI == 0 || EPI == 1) {
            float4 lo, hi;
            float* pl = (float*)&lo; float* ph = (float*)&hi;
            #pragma unroll
            for (int i = 0; i < 4; ++i) {
                float vl = acc[j][i]     + bias[n0 + tn * 4 + i];
                float vh = acc[j][4 + i] + bias[n0 + 64 + tn * 4 + i];
                if constexpr (EPI == 1) {
                    vl = 0.5f * vl * (1.f + erff(vl * 0.70710678118f));
                    vh = 0.5f * vh * (1.f + erff(vh * 0.70710678118f));
                }
                pl[i] = vl; ph[i] = vh;
            }
            *(float4*)(C + (size_t)row * ldc + n0 + tn * 4)      = lo;
            *(float4*)(C + (size_t)row * ldc + n0 + 64 + tn * 4) = hi;
        } else {
            // residual + LayerNorm (n0 == 0, ldc == 128 for this path)
            float v[8];
            float s1 = 0.f, s2 = 0.f;
            #pragma unroll
            for (int i = 0; i < 8; ++i) {
                const int col = (i < 4) ? (tn * 4 + i) : (64 + tn * 4 + (i - 4));
                float val = acc[j][i] + bias[col] + res[(size_t)row * DD + col];
                v[i] = val; s1 += val; s2 += val * val;
            }
            #pragma unroll
            for (int off = 1; off < 16; off <<= 1) {
                s1 += __shfl_xor(s1, off, 16);
                s2 += __shfl_xor(s2, off, 16);
            }
            const float mean = s1 * (1.0f / DD);
            const float var  = s2 * (1.0f / DD) - mean * mean;
            const float rstd = rsqrtf(var + LN_EPS);
            float4 lo, hi;
            float* pl = (float*)&lo; float* ph = (float*)&hi;
            #pragma unroll
            for (int i = 0; i < 4; ++i) {
                const int cl = tn * 4 + i, ch = 64 + tn * 4 + i;
                pl[i] = (v[i]     - mean) * rstd * g[cl] + bt[cl];
                ph[i] = (v[4 + i] - mean) * rstd * g[ch] + bt[ch];
            }
            *(float4*)(C + (size_t)row * DD + tn * 4)      = lo;
            *(float4*)(C + (size_t)row * DD + 64 + tn * 4) = hi;
        }
    }
}

// ---------------------------------------------------------------------------
// Windowed attention: 16 lanes per (b,h,s); window 11, softmax, weighted V.
// ---------------------------------------------------------------------------
__global__ __launch_bounds__(256) void k_attn(
    const float* __restrict__ q, const float* __restrict__ k,
    const float* __restrict__ v, float* __restrict__ ctx)
{
    const int tid  = threadIdx.x;
    const int lane = tid & 15;
    const int gid  = blockIdx.x * 16 + (tid >> 4);   // 0 .. B*H*S-1
    const int s  = gid % SS;
    const int bh = gid / SS;
    const int hh = bh % HH;
    const int b  = bh / HH;

    const size_t rowbase = ((size_t)(b * SS + s)) * DD + hh * HDIM + lane;
    const float qd = q[rowbase] * 0.25f;   // 1/sqrt(16)

    float sc[WINW];
    float mx = -INFINITY;
    #pragma unroll
    for (int w = 0; w < WINW; ++w) {
        const int sw = s + w - HALF_;
        if (sw >= 0 && sw < SS) {
            float p = qd * k[((size_t)(b * SS + sw)) * DD + hh * HDIM + lane];
            #pragma unroll
            for (int off = 1; off < 16; off <<= 1) p += __shfl_xor(p, off, 16);
            sc[w] = p;
            mx = fmaxf(mx, p);
        } else {
            sc[w] = -INFINITY;
        }
    }
    float den = 0.f;
    #pragma unroll
    for (int w = 0; w < WINW; ++w) { sc[w] = expf(sc[w] - mx); den += sc[w]; }
    const float inv = 1.f / den;

    float cd = 0.f;
    #pragma unroll
    for (int w = 0; w < WINW; ++w) {
        const int sw = s + w - HALF_;
        if (sw >= 0 && sw < SS)
            cd += sc[w] * v[((size_t)(b * SS + sw)) * DD + hh * HDIM + lane];
    }
    ctx[rowbase] = cd * inv;
}

// ---------------------------------------------------------------------------
// Final: out[b] = mean_s(h[b,s,:]) @ W_cls + b_cls
// ---------------------------------------------------------------------------
__global__ __launch_bounds__(128) void k_final(
    const float* __restrict__ h, const float* __restrict__ Wc,
    const float* __restrict__ bc, float* __restrict__ out)
{
    const int b = blockIdx.x, d = threadIdx.x;
    float p = 0.f;
    for (int s = 0; s < SS; ++s) p += h[((size_t)(b * SS + s)) * DD + d];
    p *= (1.0f / SS);
    float l0 = p * Wc[d * 2 + 0];
    float l1 = p * Wc[d * 2 + 1];
    #pragma unroll
    for (int off = 1; off < 64; off <<= 1) {
        l0 += __shfl_xor(l0, off);
        l1 += __shfl_xor(l1, off);
    }
    __shared__ float r[2][2];
    const int wid = d >> 6;
    if ((d & 63) == 0) { r[wid][0] = l0; r[wid][1] = l1; }
    __syncthreads();
    if (d == 0) {
        out[b * 2 + 0] = r[0][0] + r[1][0] + bc[0];
        out[b * 2 + 1] = r[0][1] + r[1][1] + bc[1];
    }
}

// ---------------------------------------------------------------------------
extern "C" void kernel_launch(void* const* d_in, const int* in_sizes, int n_in,
                              void* d_out, int out_size, void* d_ws, size_t ws_size,
                              hipStream_t stream)
{
    const float* x      = (const float*)d_in[0];
    const float* W_in   = (const float*)d_in[1];
    const float* b_in   = (const float*)d_in[2];
    const float* pos    = (const float*)d_in[3];
    const float* tt     = (const float*)d_in[4];
    const float* lng    = (const float*)d_in[5];
    const float* lnb    = (const float*)d_in[6];
    const float* Wq     = (const float*)d_in[7];
    const float* bq     = (const float*)d_in[8];
    const float* Wk     = (const float*)d_in[9];
    const float* bk     = (const float*)d_in[10];
    const float* Wv     = (const float*)d_in[11];
    const float* bv     = (const float*)d_in[12];
    const float* Wo     = (const float*)d_in[13];
    const float* bo     = (const float*)d_in[14];
    const float* ln1g   = (const float*)d_in[15];
    const float* ln1b   = (const float*)d_in[16];
    const float* Wi     = (const float*)d_in[17];
    const float* bi     = (const float*)d_in[18];
    const float* Wo2    = (const float*)d_in[19];
    const float* bo2    = (const float*)d_in[20];
    const float* ln2g   = (const float*)d_in[21];
    const float* ln2b   = (const float*)d_in[22];
    const float* Wc     = (const float*)d_in[23];
    const float* bc     = (const float*)d_in[24];

    float* ws  = (float*)d_ws;
    float* h   = ws;                       // 4,096,000 floats
    float* ctx = ws + 4096000;             // 4,096,000
    float* q   = ws + 8192000;             // 4,096,000
    float* kk  = ws + 12288000;            // 4,096,000
    float* vv  = ws + 16384000;            // 4,096,000
    float* hid = ws + 8192000;             // 16,384,000 (aliases q/k/v, dead by FFN)

    k_embed<<<MM, 128, 0, stream>>>(x, W_in, b_in, pos, tt, lng, lnb, h);

    for (int l = 0; l < LL; ++l) {
        const float* Wq_l = Wq + (size_t)l * DD * DD;
        const float* Wk_l = Wk + (size_t)l * DD * DD;
        const float* Wv_l = Wv + (size_t)l * DD * DD;
        const float* Wo_l = Wo + (size_t)l * DD * DD;
        const float* Wi_l = Wi + (size_t)l * DD * FF;
        const float* W2_l = Wo2 + (size_t)l * FF * DD;

        k_gemm<0><<<dim3(MM / 64, 1), 256, 0, stream>>>(
            h, DD, DD, Wq_l, DD, bq + l * DD, nullptr, nullptr, nullptr, q, DD);
        k_gemm<0><<<dim3(MM / 64, 1), 256, 0, stream>>>(
            h, DD, DD, Wk_l, DD, bk + l * DD, nullptr, nullptr, nullptr, kk, DD);
        k_gemm<0><<<dim3(MM / 64, 1), 256, 0, stream>>>(
            h, DD, DD, Wv_l, DD, bv + l * DD, nullptr, nullptr, nullptr, vv, DD);

        k_attn<<<(BB * HH * SS) / 16, 256, 0, stream>>>(q, kk, vv, ctx);

        k_gemm<2><<<dim3(MM / 64, 1), 256, 0, stream>>>(
            ctx, DD, DD, Wo_l, DD, bo + l * DD, h, ln1g + l * DD, ln1b + l * DD, h, DD);

        k_gemm<1><<<dim3(MM / 64, 4), 256, 0, stream>>>(
            h, DD, DD, Wi_l, FF, bi + l * FF, nullptr, nullptr, nullptr, hid, FF);

        k_gemm<2><<<dim3(MM / 64, 1), 256, 0, stream>>>(
            hid, FF, FF, W2_l, DD, bo2 + l * DD, h, ln2g + l * DD, ln2b + l * DD, h, DD);
    }

    k_final<<<BB, 128, 0, stream>>>(h, Wc, bc, (float*)d_out);
}

// Round 2
// 692.058 us; speedup vs baseline: 1.1605x; 1.1605x over previous
//
#include <hip/hip_runtime.h>
#include <math.h>

#define BB 64
#define SS 500
#define DIN 64
#define DD 128
#define HH 8
#define HDIM 16
#define HALF_ 5
#define WINW 11
#define LL 2
#define FF 512
#define MM (BB*SS)          // 32000 rows
#define LN_EPS 1e-12f

// ---------------------------------------------------------------------------
// Embedding: h = LN(x @ W_in + b_in + pos_emb[2+s] + tt_emb)
// 256 threads, 16 rows per block; W_in staged in LDS (32 KB) once per block.
// ---------------------------------------------------------------------------
__global__ __launch_bounds__(256) void k_embed(
    const float* __restrict__ x, const float* __restrict__ Win,
    const float* __restrict__ bin, const float* __restrict__ pos,
    const float* __restrict__ tt, const float* __restrict__ g,
    const float* __restrict__ be, float* __restrict__ h)
{
    __shared__ float WinS[DIN][DD];   // 32 KB
    __shared__ float xs[16][DIN];     // 4 KB
    __shared__ float rs[4][2];

    const int tid = threadIdx.x;
    const int d    = tid & 127;       // output dim
    const int rp   = tid >> 7;        // 0/1: which of 2 concurrent rows
    const int wid  = tid >> 6;        // 0..3
    const int row0 = blockIdx.x * 16;

    // stage W_in: 8192 floats, 256 thr * 4 = 1024/iter
    #pragma unroll
    for (int it = 0; it < 8; ++it) {
        int lin = it * 1024 + tid * 4;
        *(float4*)&WinS[lin >> 7][lin & 127] = *(const float4*)(Win + lin);
    }
    // stage x rows: 16*64 = 1024 floats
    {
        int lin = tid * 4;
        *(float4*)&xs[lin >> 6][lin & 63] =
            *(const float4*)(x + (size_t)row0 * DIN + lin);
    }
    __syncthreads();

    const float bd = bin[d] + tt[d];

    for (int it = 0; it < 8; ++it) {
        const int r   = it * 2 + rp;          // 0..15
        const int row = row0 + r;
        const int s   = row % SS;

        float acc = bd + pos[(size_t)(2 + s) * DD + d];
        #pragma unroll 8
        for (int i = 0; i < DIN; ++i) acc += xs[r][i] * WinS[i][d];

        float s1 = acc, s2 = acc * acc;
        #pragma unroll
        for (int off = 1; off < 64; off <<= 1) {
            s1 += __shfl_xor(s1, off);
            s2 += __shfl_xor(s2, off);
        }
        if ((tid & 63) == 0) { rs[wid][0] = s1; rs[wid][1] = s2; }
        __syncthreads();
        const float S1 = rs[rp * 2][0] + rs[rp * 2 + 1][0];
        const float S2 = rs[rp * 2][1] + rs[rp * 2 + 1][1];
        const float mean = S1 * (1.0f / DD);
        const float var  = S2 * (1.0f / DD) - mean * mean;
        const float rstd = rsqrtf(var + LN_EPS);
        h[(size_t)row * DD + d] = (acc - mean) * rstd * g[d] + be[d];
        __syncthreads();
    }
}

// ---------------------------------------------------------------------------
// GEMM core: 64x128 tile, BK=64 streamed, 256 threads, per-thread 4m x 8n.
// LDS = 64*68*4 + 64*128*4 = 49.7 KB -> 3 blocks/CU (12 waves/CU).
// ---------------------------------------------------------------------------
#define GEMM_BODY(A, lda, K, W, ldw, n0)                                      \
    __shared__ float As[64][68];                                              \
    __shared__ float Ws[64][128];                                             \
    const int tid = threadIdx.x;                                              \
    const int tn = tid & 15;                                                  \
    const int tm = tid >> 4;                                                  \
    const int m0 = blockIdx.x * 64;                                           \
    float acc[4][8];                                                          \
    _Pragma("unroll")                                                         \
    for (int j = 0; j < 4; ++j)                                               \
        _Pragma("unroll")                                                     \
        for (int i = 0; i < 8; ++i) acc[j][i] = 0.f;                          \
    for (int k0 = 0; k0 < (K); k0 += 64) {                                    \
        _Pragma("unroll")                                                     \
        for (int it = 0; it < 4; ++it) {                                      \
            int lin = it * 1024 + tid * 4;                                    \
            int r = lin >> 6, c = lin & 63;                                   \
            *(float4*)&As[r][c] =                                             \
                *(const float4*)((A) + (size_t)(m0 + r) * (lda) + k0 + c);    \
        }                                                                     \
        _Pragma("unroll")                                                     \
        for (int it = 0; it < 8; ++it) {                                      \
            int lin = it * 1024 + tid * 4;                                    \
            int r = lin >> 7, c = lin & 127;                                  \
            *(float4*)&Ws[r][c] =                                             \
                *(const float4*)((W) + (size_t)(k0 + r) * (ldw) + (n0) + c);  \
        }                                                                     \
        __syncthreads();                                                      \
        _Pragma("unroll 4")                                                   \
        for (int kk = 0; kk < 64; kk += 4) {                                  \
            float4 a4[4];                                                     \
            _Pragma("unroll")                                                 \
            for (int j = 0; j < 4; ++j)                                       \
                a4[j] = *(const float4*)&As[tm * 4 + j][kk];                  \
            _Pragma("unroll")                                                 \
            for (int t = 0; t < 4; ++t) {                                     \
                float4 wlo = *(const float4*)&Ws[kk + t][tn * 4];             \
                float4 whi = *(const float4*)&Ws[kk + t][64 + tn * 4];        \
                _Pragma("unroll")                                             \
                for (int j = 0; j < 4; ++j) {                                 \
                    float av = ((const float*)&a4[j])[t];                     \
                    acc[j][0] += av * wlo.x; acc[j][1] += av * wlo.y;         \
                    acc[j][2] += av * wlo.z; acc[j][3] += av * wlo.w;         \
                    acc[j][4] += av * whi.x; acc[j][5] += av * whi.y;         \
                    acc[j][6] += av * whi.z; acc[j][7] += av * whi.w;         \
                }                                                             \
            }                                                                 \
        }                                                                     \
        __syncthreads();                                                      \
    }

// plain / gelu epilogue
template<int EPI>   // 0 = bias, 1 = bias+gelu
__global__ __launch_bounds__(256, 3) void k_gemm(
    const float* __restrict__ A, int lda, int K,
    const float* __restrict__ W, int ldw,
    const float* __restrict__ bias,
    float* __restrict__ C, int ldc)
{
    const int n0 = blockIdx.y * 128;
    GEMM_BODY(A, lda, K, W, ldw, n0)
    #pragma unroll
    for (int j = 0; j < 4; ++j) {
        const int row = m0 + tm * 4 + j;
        float4 lo, hi;
        float* pl = (float*)&lo; float* ph = (float*)&hi;
        #pragma unroll
        for (int i = 0; i < 4; ++i) {
            float vl = acc[j][i]     + bias[n0 + tn * 4 + i];
            float vh = acc[j][4 + i] + bias[n0 + 64 + tn * 4 + i];
            if constexpr (EPI == 1) {
                vl = 0.5f * vl * (1.f + erff(vl * 0.70710678118f));
                vh = 0.5f * vh * (1.f + erff(vh * 0.70710678118f));
            }
            pl[i] = vl; ph[i] = vh;
        }
        *(float4*)(C + (size_t)row * ldc + n0 + tn * 4)      = lo;
        *(float4*)(C + (size_t)row * ldc + n0 + 64 + tn * 4) = hi;
    }
}

// residual + LayerNorm epilogue (N == 128, n0 == 0)
__global__ __launch_bounds__(256, 3) void k_gemm_ln(
    const float* __restrict__ A, int lda, int K,
    const float* __restrict__ W, int ldw,
    const float* __restrict__ bias,
    const float* __restrict__ res,
    const float* __restrict__ g, const float* __restrict__ bt,
    float* __restrict__ C)
{
    GEMM_BODY(A, lda, K, W, ldw, 0)
    #pragma unroll
    for (int j = 0; j < 4; ++j) {
        const int row = m0 + tm * 4 + j;
        float v[8];
        float s1 = 0.f, s2 = 0.f;
        #pragma unroll
        for (int i = 0; i < 8; ++i) {
            const int col = (i < 4) ? (tn * 4 + i) : (64 + tn * 4 + (i - 4));
            float val = acc[j][i] + bias[col] + res[(size_t)row * DD + col];
            v[i] = val; s1 += val; s2 += val * val;
        }
        #pragma unroll
        for (int off = 1; off < 16; off <<= 1) {
            s1 += __shfl_xor(s1, off, 16);
            s2 += __shfl_xor(s2, off, 16);
        }
        const float mean = s1 * (1.0f / DD);
        const float var  = s2 * (1.0f / DD) - mean * mean;
        const float rstd = rsqrtf(var + LN_EPS);
        float4 lo, hi;
        float* pl = (float*)&lo; float* ph = (float*)&hi;
        #pragma unroll
        for (int i = 0; i < 4; ++i) {
            const int cl = tn * 4 + i, ch = 64 + tn * 4 + i;
            pl[i] = (v[i]     - mean) * rstd * g[cl] + bt[cl];
            ph[i] = (v[4 + i] - mean) * rstd * g[ch] + bt[ch];
        }
        *(float4*)(C + (size_t)row * DD + tn * 4)      = lo;
        *(float4*)(C + (size_t)row * DD + 64 + tn * 4) = hi;
    }
}

// fused QKV: blockIdx.y picks (Wq,bq,q) / (Wk,bk,k) / (Wv,bv,v)
__global__ __launch_bounds__(256, 3) void k_gemm_qkv(
    const float* __restrict__ A,
    const float* __restrict__ Wq, const float* __restrict__ bq, float* __restrict__ q,
    const float* __restrict__ Wk, const float* __restrict__ bk, float* __restrict__ k,
    const float* __restrict__ Wv, const float* __restrict__ bv, float* __restrict__ v)
{
    const float* W; const float* bias; float* C;
    if (blockIdx.y == 0)      { W = Wq; bias = bq; C = q; }
    else if (blockIdx.y == 1) { W = Wk; bias = bk; C = k; }
    else                      { W = Wv; bias = bv; C = v; }
    GEMM_BODY(A, DD, DD, W, DD, 0)
    #pragma unroll
    for (int j = 0; j < 4; ++j) {
        const int row = m0 + tm * 4 + j;
        float4 lo, hi;
        float* pl = (float*)&lo; float* ph = (float*)&hi;
        #pragma unroll
        for (int i = 0; i < 4; ++i) {
            pl[i] = acc[j][i]     + bias[tn * 4 + i];
            ph[i] = acc[j][4 + i] + bias[64 + tn * 4 + i];
        }
        *(float4*)(C + (size_t)row * DD + tn * 4)      = lo;
        *(float4*)(C + (size_t)row * DD + 64 + tn * 4) = hi;
    }
}

// ---------------------------------------------------------------------------
// Windowed attention: 16 lanes per (b,h,s); window 11, softmax, weighted V.
// ---------------------------------------------------------------------------
__global__ __launch_bounds__(256) void k_attn(
    const float* __restrict__ q, const float* __restrict__ k,
    const float* __restrict__ v, float* __restrict__ ctx)
{
    const int tid  = threadIdx.x;
    const int lane = tid & 15;
    const int gid  = blockIdx.x * 16 + (tid >> 4);   // 0 .. B*H*S-1
    const int s  = gid % SS;
    const int bh = gid / SS;
    const int hh = bh % HH;
    const int b  = bh / HH;

    const size_t rowbase = ((size_t)(b * SS + s)) * DD + hh * HDIM + lane;
    const float qd = q[rowbase] * 0.25f;   // 1/sqrt(16)

    float sc[WINW];
    float mx = -INFINITY;
    #pragma unroll
    for (int w = 0; w < WINW; ++w) {
        const int sw = s + w - HALF_;
        if (sw >= 0 && sw < SS) {
            float p = qd * k[((size_t)(b * SS + sw)) * DD + hh * HDIM + lane];
            #pragma unroll
            for (int off = 1; off < 16; off <<= 1) p += __shfl_xor(p, off, 16);
            sc[w] = p;
            mx = fmaxf(mx, p);
        } else {
            sc[w] = -INFINITY;
        }
    }
    float den = 0.f;
    #pragma unroll
    for (int w = 0; w < WINW; ++w) { sc[w] = expf(sc[w] - mx); den += sc[w]; }
    const float inv = 1.f / den;

    float cd = 0.f;
    #pragma unroll
    for (int w = 0; w < WINW; ++w) {
        const int sw = s + w - HALF_;
        if (sw >= 0 && sw < SS)
            cd += sc[w] * v[((size_t)(b * SS + sw)) * DD + hh * HDIM + lane];
    }
    ctx[rowbase] = cd * inv;
}

// ---------------------------------------------------------------------------
// Final: out[b] = mean_s(h[b,s,:]) @ W_cls + b_cls
// ---------------------------------------------------------------------------
__global__ __launch_bounds__(128) void k_final(
    const float* __restrict__ h, const float* __restrict__ Wc,
    const float* __restrict__ bc, float* __restrict__ out)
{
    const int b = blockIdx.x, d = threadIdx.x;
    float p = 0.f;
    for (int s = 0; s < SS; ++s) p += h[((size_t)(b * SS + s)) * DD + d];
    p *= (1.0f / SS);
    float l0 = p * Wc[d * 2 + 0];
    float l1 = p * Wc[d * 2 + 1];
    #pragma unroll
    for (int off = 1; off < 64; off <<= 1) {
        l0 += __shfl_xor(l0, off);
        l1 += __shfl_xor(l1, off);
    }
    __shared__ float r[2][2];
    const int wid = d >> 6;
    if ((d & 63) == 0) { r[wid][0] = l0; r[wid][1] = l1; }
    __syncthreads();
    if (d == 0) {
        out[b * 2 + 0] = r[0][0] + r[1][0] + bc[0];
        out[b * 2 + 1] = r[0][1] + r[1][1] + bc[1];
    }
}

// ---------------------------------------------------------------------------
extern "C" void kernel_launch(void* const* d_in, const int* in_sizes, int n_in,
                              void* d_out, int out_size, void* d_ws, size_t ws_size,
                              hipStream_t stream)
{
    const float* x      = (const float*)d_in[0];
    const float* W_in   = (const float*)d_in[1];
    const float* b_in   = (const float*)d_in[2];
    const float* pos    = (const float*)d_in[3];
    const float* tt     = (const float*)d_in[4];
    const float* lng    = (const float*)d_in[5];
    const float* lnb    = (const float*)d_in[6];
    const float* Wq     = (const float*)d_in[7];
    const float* bq     = (const float*)d_in[8];
    const float* Wk     = (const float*)d_in[9];
    const float* bk     = (const float*)d_in[10];
    const float* Wv     = (const float*)d_in[11];
    const float* bv     = (const float*)d_in[12];
    const float* Wo     = (const float*)d_in[13];
    const float* bo     = (const float*)d_in[14];
    const float* ln1g   = (const float*)d_in[15];
    const float* ln1b   = (const float*)d_in[16];
    const float* Wi     = (const float*)d_in[17];
    const float* bi     = (const float*)d_in[18];
    const float* Wo2    = (const float*)d_in[19];
    const float* bo2    = (const float*)d_in[20];
    const float* ln2g   = (const float*)d_in[21];
    const float* ln2b   = (const float*)d_in[22];
    const float* Wc     = (const float*)d_in[23];
    const float* bc     = (const float*)d_in[24];

    float* ws  = (float*)d_ws;
    float* h   = ws;                       // 4,096,000 floats
    float* ctx = ws + 4096000;             // 4,096,000
    float* q   = ws + 8192000;             // 4,096,000
    float* kk  = ws + 12288000;            // 4,096,000
    float* vv  = ws + 16384000;            // 4,096,000
    float* hid = ws + 8192000;             // 16,384,000 (aliases q/k/v, dead by FFN)

    k_embed<<<MM / 16, 256, 0, stream>>>(x, W_in, b_in, pos, tt, lng, lnb, h);

    for (int l = 0; l < LL; ++l) {
        const float* Wq_l = Wq + (size_t)l * DD * DD;
        const float* Wk_l = Wk + (size_t)l * DD * DD;
        const float* Wv_l = Wv + (size_t)l * DD * DD;
        const float* Wo_l = Wo + (size_t)l * DD * DD;
        const float* Wi_l = Wi + (size_t)l * DD * FF;
        const float* W2_l = Wo2 + (size_t)l * FF * DD;

        k_gemm_qkv<<<dim3(MM / 64, 3), 256, 0, stream>>>(
            h, Wq_l, bq + l * DD, q, Wk_l, bk + l * DD, kk, Wv_l, bv + l * DD, vv);

        k_attn<<<(BB * HH * SS) / 16, 256, 0, stream>>>(q, kk, vv, ctx);

        k_gemm_ln<<<dim3(MM / 64, 1), 256, 0, stream>>>(
            ctx, DD, DD, Wo_l, DD, bo + l * DD, h, ln1g + l * DD, ln1b + l * DD, h);

        k_gemm<1><<<dim3(MM / 64, 4), 256, 0, stream>>>(
            h, DD, DD, Wi_l, FF, bi + l * FF, hid, FF);

        k_gemm_ln<<<dim3(MM / 64, 1), 256, 0, stream>>>(
            hid, FF, FF, W2_l, DD, bo2 + l * DD, h, ln2g + l * DD, ln2b + l * DD, h);
    }

    k_final<<<BB, 128, 0, stream>>>(h, Wc, bc, (float*)d_out);
}

// Round 3
// 386.698 us; speedup vs baseline: 2.0770x; 1.7897x over previous
//
#include <hip/hip_runtime.h>
#include <hip/hip_bf16.h>
#include <math.h>

#define BB 64
#define SS 500
#define DIN 64
#define DD 128
#define HH 8
#define HDIM 16
#define HALF_ 5
#define WINW 11
#define LL 2
#define FF 512
#define MM (BB*SS)          // 32000 rows
#define LN_EPS 1e-12f

typedef __attribute__((ext_vector_type(8))) short short8;   // 8 bf16 = 4 VGPR
typedef __attribute__((ext_vector_type(4))) float f32x4;

// ---------------------------------------------------------------------------
// Weight prep: convert fp32 W[K][N] -> bf16 W^T[N][K], all 12 matrices.
// ---------------------------------------------------------------------------
__global__ __launch_bounds__(256) void k_prep(
    const float* __restrict__ Wq, const float* __restrict__ Wk,
    const float* __restrict__ Wv, const float* __restrict__ Wo,
    const float* __restrict__ Wi, const float* __restrict__ Wo2,
    __hip_bfloat16* __restrict__ wT)
{
    const int m = blockIdx.y;        // 0..11
    const int l = m / 6, t = m % 6;
    const float* src; int Kd, Nd, kshift, doff;
    switch (t) {
      case 0:  src = Wq  + l*16384; Kd=128; Nd=128; kshift=7; doff=0;      break;
      case 1:  src = Wk  + l*16384; Kd=128; Nd=128; kshift=7; doff=16384;  break;
      case 2:  src = Wv  + l*16384; Kd=128; Nd=128; kshift=7; doff=32768;  break;
      case 3:  src = Wo  + l*16384; Kd=128; Nd=128; kshift=7; doff=49152;  break;
      case 4:  src = Wi  + l*65536; Kd=128; Nd=512; kshift=7; doff=65536;  break;
      default: src = Wo2 + l*65536; Kd=512; Nd=128; kshift=9; doff=131072; break;
    }
    __hip_bfloat16* dst = wT + l*196608 + doff;
    const int NK = Kd * Nd;
    int e = (blockIdx.x * 256 + threadIdx.x) * 4;
    if (e >= NK) return;
    #pragma unroll
    for (int j = 0; j < 4; ++j, ++e) {
        int n = e >> kshift, kx = e & (Kd - 1);
        dst[(size_t)n * Kd + kx] = __float2bfloat16(src[(size_t)kx * Nd + n]);
    }
}

// ---------------------------------------------------------------------------
// Embedding: h = LN(x @ W_in + b_in + pos_emb[2+s] + tt_emb); dual store.
// ---------------------------------------------------------------------------
__global__ __launch_bounds__(256) void k_embed(
    const float* __restrict__ x, const float* __restrict__ Win,
    const float* __restrict__ bin, const float* __restrict__ pos,
    const float* __restrict__ tt, const float* __restrict__ g,
    const float* __restrict__ be, float* __restrict__ h,
    __hip_bfloat16* __restrict__ hbf)
{
    __shared__ float WinS[DIN][DD];   // 32 KB
    __shared__ float xs[16][DIN];     // 4 KB
    __shared__ float rs[4][2];

    const int tid = threadIdx.x;
    const int d    = tid & 127;
    const int rp   = tid >> 7;
    const int wid  = tid >> 6;
    const int row0 = blockIdx.x * 16;

    #pragma unroll
    for (int it = 0; it < 8; ++it) {
        int lin = it * 1024 + tid * 4;
        *(float4*)&WinS[lin >> 7][lin & 127] = *(const float4*)(Win + lin);
    }
    {
        int lin = tid * 4;
        *(float4*)&xs[lin >> 6][lin & 63] =
            *(const float4*)(x + (size_t)row0 * DIN + lin);
    }
    __syncthreads();

    const float bd = bin[d] + tt[d];

    for (int it = 0; it < 8; ++it) {
        const int r   = it * 2 + rp;
        const int row = row0 + r;
        const int s   = row % SS;

        float acc = bd + pos[(size_t)(2 + s) * DD + d];
        #pragma unroll 8
        for (int i = 0; i < DIN; ++i) acc += xs[r][i] * WinS[i][d];

        float s1 = acc, s2 = acc * acc;
        #pragma unroll
        for (int off = 1; off < 64; off <<= 1) {
            s1 += __shfl_xor(s1, off);
            s2 += __shfl_xor(s2, off);
        }
        if ((tid & 63) == 0) { rs[wid][0] = s1; rs[wid][1] = s2; }
        __syncthreads();
        const float S1 = rs[rp * 2][0] + rs[rp * 2 + 1][0];
        const float S2 = rs[rp * 2][1] + rs[rp * 2 + 1][1];
        const float mean = S1 * (1.0f / DD);
        const float var  = S2 * (1.0f / DD) - mean * mean;
        const float rstd = rsqrtf(var + LN_EPS);
        const float o = (acc - mean) * rstd * g[d] + be[d];
        h[(size_t)row * DD + d]   = o;
        hbf[(size_t)row * DD + d] = __float2bfloat16(o);
        __syncthreads();
    }
}

// ---------------------------------------------------------------------------
// MFMA GEMM mainloop: block = 128 rows x 128 cols, 4 row-waves (32 rows each),
// 16x16x32 bf16 MFMA, BK=64. A: bf16 [M][lda]; W: bf16 W^T [N][ldw].
// LDS stride 72 bf16 = 144 B: 16B-aligned, bank-balanced reads+writes.
// ---------------------------------------------------------------------------
#define GEMM_MAIN(Abf, lda, Kdim, WTbf, ldw, n0w)                             \
    __shared__ __align__(16) __hip_bfloat16 As[128][72];                      \
    __shared__ __align__(16) __hip_bfloat16 Ws[128][72];                      \
    const int tid = threadIdx.x;                                              \
    const int wid = tid >> 6;                                                 \
    const int l15 = tid & 15;                                                 \
    const int l4  = (tid & 63) >> 4;                                          \
    const int m0  = blockIdx.x * 128;                                         \
    f32x4 acc[2][8];                                                          \
    _Pragma("unroll")                                                         \
    for (int m = 0; m < 2; ++m)                                               \
        _Pragma("unroll")                                                     \
        for (int n = 0; n < 8; ++n) acc[m][n] = (f32x4){0.f, 0.f, 0.f, 0.f};  \
    for (int k0 = 0; k0 < (Kdim); k0 += 64) {                                 \
        _Pragma("unroll")                                                     \
        for (int it = 0; it < 4; ++it) {                                      \
            int lin = it * 2048 + tid * 8;                                    \
            int r = lin >> 6, c = lin & 63;                                   \
            *(uint4*)&As[r][c] =                                              \
                *(const uint4*)((Abf) + (size_t)(m0 + r) * (lda) + k0 + c);   \
            *(uint4*)&Ws[r][c] =                                              \
                *(const uint4*)((WTbf) + (size_t)((n0w) + r) * (ldw) + k0 + c); \
        }                                                                     \
        __syncthreads();                                                      \
        for (int kc = 0; kc < 64; kc += 32) {                                 \
            short8 a0 = *(const short8*)&As[wid * 32 +      l15][kc + l4 * 8];\
            short8 a1 = *(const short8*)&As[wid * 32 + 16 + l15][kc + l4 * 8];\
            _Pragma("unroll")                                                 \
            for (int n = 0; n < 8; ++n) {                                     \
                short8 bf = *(const short8*)&Ws[n * 16 + l15][kc + l4 * 8];   \
                acc[0][n] = __builtin_amdgcn_mfma_f32_16x16x32_bf16(a0, bf, acc[0][n], 0, 0, 0); \
                acc[1][n] = __builtin_amdgcn_mfma_f32_16x16x32_bf16(a1, bf, acc[1][n], 0, 0, 0); \
            }                                                                 \
        }                                                                     \
        __syncthreads();                                                      \
    }
// acc[m][n][q] -> row = m0 + wid*32 + m*16 + l4*4 + q, col = n*16 + l15

// fused QKV (N=128 each, blockIdx.y selects q/k/v), fp32 out
__global__ __launch_bounds__(256, 4) void k_gemm_qkv(
    const __hip_bfloat16* __restrict__ hbf,
    const __hip_bfloat16* __restrict__ wTq, const __hip_bfloat16* __restrict__ wTk,
    const __hip_bfloat16* __restrict__ wTv,
    const float* __restrict__ bq, const float* __restrict__ bk,
    const float* __restrict__ bv,
    float* __restrict__ q, float* __restrict__ k, float* __restrict__ v)
{
    const __hip_bfloat16* WT; const float* bias; float* out;
    if (blockIdx.y == 0)      { WT = wTq; bias = bq; out = q; }
    else if (blockIdx.y == 1) { WT = wTk; bias = bk; out = k; }
    else                      { WT = wTv; bias = bv; out = v; }
    GEMM_MAIN(hbf, DD, DD, WT, DD, 0)
    #pragma unroll
    for (int m = 0; m < 2; ++m)
        #pragma unroll
        for (int qq = 0; qq < 4; ++qq) {
            const int row = m0 + wid * 32 + m * 16 + l4 * 4 + qq;
            #pragma unroll
            for (int n = 0; n < 8; ++n) {
                const int col = n * 16 + l15;
                out[(size_t)row * DD + col] = acc[m][n][qq] + bias[col];
            }
        }
}

// FFN1: N=512 tiled by blockIdx.y, gelu(exact), bf16 out
__global__ __launch_bounds__(256, 4) void k_gemm_gelu(
    const __hip_bfloat16* __restrict__ hbf,
    const __hip_bfloat16* __restrict__ wTi,
    const float* __restrict__ bias, __hip_bfloat16* __restrict__ hid)
{
    const int n0g = blockIdx.y * 128;
    GEMM_MAIN(hbf, DD, DD, wTi, DD, n0g)
    #pragma unroll
    for (int m = 0; m < 2; ++m)
        #pragma unroll
        for (int qq = 0; qq < 4; ++qq) {
            const int row = m0 + wid * 32 + m * 16 + l4 * 4 + qq;
            #pragma unroll
            for (int n = 0; n < 8; ++n) {
                const int col = n0g + n * 16 + l15;
                float val = acc[m][n][qq] + bias[col];
                val = 0.5f * val * (1.f + erff(val * 0.70710678118f));
                hid[(size_t)row * FF + col] = __float2bfloat16(val);
            }
        }
}

// GEMM + bias + residual + LayerNorm, dual store (N=128)
__global__ __launch_bounds__(256, 4) void k_gemm_lnres(
    const __hip_bfloat16* __restrict__ Abf, int lda, int Kdim,
    const __hip_bfloat16* __restrict__ WT,
    const float* __restrict__ bias, const float* __restrict__ res,
    const float* __restrict__ g, const float* __restrict__ bt,
    float* __restrict__ outF, __hip_bfloat16* __restrict__ outB)
{
    GEMM_MAIN(Abf, lda, Kdim, WT, Kdim, 0)
    #pragma unroll
    for (int m = 0; m < 2; ++m)
        #pragma unroll
        for (int qq = 0; qq < 4; ++qq) {
            const int row = m0 + wid * 32 + m * 16 + l4 * 4 + qq;
            float vals[8]; float s1 = 0.f, s2 = 0.f;
            #pragma unroll
            for (int n = 0; n < 8; ++n) {
                const int col = n * 16 + l15;
                float val = acc[m][n][qq] + bias[col] + res[(size_t)row * DD + col];
                vals[n] = val; s1 += val; s2 += val * val;
            }
            #pragma unroll
            for (int off = 1; off < 16; off <<= 1) {
                s1 += __shfl_xor(s1, off, 16);
                s2 += __shfl_xor(s2, off, 16);
            }
            const float mean = s1 * (1.0f / DD);
            const float var  = s2 * (1.0f / DD) - mean * mean;
            const float rstd = rsqrtf(var + LN_EPS);
            #pragma unroll
            for (int n = 0; n < 8; ++n) {
                const int col = n * 16 + l15;
                const float o = (vals[n] - mean) * rstd * g[col] + bt[col];
                outF[(size_t)row * DD + col] = o;
                outB[(size_t)row * DD + col] = __float2bfloat16(o);
            }
        }
}

// ---------------------------------------------------------------------------
// Windowed attention, LDS-staged: block = (s-tile of 16, h, b), 256 thr =
// 16 groups x 16 lanes. Phase 1: lane=w (one score each, 1 exp). Phase 2:
// lane=d (PV). Writes ctx directly as bf16.
// ---------------------------------------------------------------------------
__global__ __launch_bounds__(256) void k_attn(
    const float* __restrict__ q, const float* __restrict__ k,
    const float* __restrict__ v, __hip_bfloat16* __restrict__ ctx)
{
    __shared__ float kS[26][17], vS[26][17], qS[16][17], pS[16][16];

    const int tile = blockIdx.x, hh = blockIdx.y, b = blockIdx.z;
    const int s0  = tile * 16;
    const int tid = threadIdx.x;

    // stage K/V rows s0-5 .. s0+20 (26 rows x 16 dims), zero-pad OOB
    for (int e = tid; e < 26 * 16; e += 256) {
        const int r = e >> 4, d = e & 15;
        const int sr = s0 - 5 + r;
        const bool ok = (sr >= 0) && (sr < SS);
        const size_t src = ((size_t)(b * SS + (ok ? sr : 0))) * DD + hh * HDIM + d;
        kS[r][d] = ok ? k[src] : 0.f;
        vS[r][d] = ok ? v[src] : 0.f;
    }
    { // stage Q rows s0..s0+15
        const int gg = tid >> 4, d = tid & 15;
        const int sq = s0 + gg;
        qS[gg][d] = (sq < SS) ? q[((size_t)(b * SS + sq)) * DD + hh * HDIM + d] : 0.f;
    }
    __syncthreads();

    const int g = tid >> 4;          // query within tile
    const int w = tid & 15;          // window pos (0..10 valid) / later: dim d
    const int sq = s0 + g;
    const int sw = sq + w - HALF_;
    const bool valid = (w < WINW) && (sw >= 0) && (sw < SS) && (sq < SS);

    // phase 1: one score per lane
    float sc = 0.f;
    #pragma unroll
    for (int d = 0; d < HDIM; ++d) sc += qS[g][d] * kS[g + w][d];
    sc = valid ? sc * 0.25f : -INFINITY;

    float mx = sc;
    #pragma unroll
    for (int off = 1; off < 16; off <<= 1) mx = fmaxf(mx, __shfl_xor(mx, off, 16));
    float p = valid ? __expf(sc - mx) : 0.f;
    float den = p;
    #pragma unroll
    for (int off = 1; off < 16; off <<= 1) den += __shfl_xor(den, off, 16);
    pS[g][w] = p / den;              // NaN only for fully-invalid queries (never stored)

    // phase 2: lane = dim
    float cd = 0.f;
    #pragma unroll
    for (int w2 = 0; w2 < WINW; ++w2) cd += pS[g][w2] * vS[g + w2][w];
    if (sq < SS)
        ctx[((size_t)(b * SS + sq)) * DD + hh * HDIM + w] = __float2bfloat16(cd);
}

// ---------------------------------------------------------------------------
// Final: out[b] = mean_s(h[b,s,:]) @ W_cls + b_cls   (fp32 exact)
// ---------------------------------------------------------------------------
__global__ __launch_bounds__(128) void k_final(
    const float* __restrict__ h, const float* __restrict__ Wc,
    const float* __restrict__ bc, float* __restrict__ out)
{
    const int b = blockIdx.x, d = threadIdx.x;
    float p = 0.f;
    for (int s = 0; s < SS; ++s) p += h[((size_t)(b * SS + s)) * DD + d];
    p *= (1.0f / SS);
    float l0 = p * Wc[d * 2 + 0];
    float l1 = p * Wc[d * 2 + 1];
    #pragma unroll
    for (int off = 1; off < 64; off <<= 1) {
        l0 += __shfl_xor(l0, off);
        l1 += __shfl_xor(l1, off);
    }
    __shared__ float r[2][2];
    const int wid = d >> 6;
    if ((d & 63) == 0) { r[wid][0] = l0; r[wid][1] = l1; }
    __syncthreads();
    if (d == 0) {
        out[b * 2 + 0] = r[0][0] + r[1][0] + bc[0];
        out[b * 2 + 1] = r[0][1] + r[1][1] + bc[1];
    }
}

// ---------------------------------------------------------------------------
extern "C" void kernel_launch(void* const* d_in, const int* in_sizes, int n_in,
                              void* d_out, int out_size, void* d_ws, size_t ws_size,
                              hipStream_t stream)
{
    const float* x      = (const float*)d_in[0];
    const float* W_in   = (const float*)d_in[1];
    const float* b_in   = (const float*)d_in[2];
    const float* pos    = (const float*)d_in[3];
    const float* tt     = (const float*)d_in[4];
    const float* lng    = (const float*)d_in[5];
    const float* lnb    = (const float*)d_in[6];
    const float* Wq     = (const float*)d_in[7];
    const float* bq     = (const float*)d_in[8];
    const float* Wk     = (const float*)d_in[9];
    const float* bk     = (const float*)d_in[10];
    const float* Wv     = (const float*)d_in[11];
    const float* bv     = (const float*)d_in[12];
    const float* Wo     = (const float*)d_in[13];
    const float* bo     = (const float*)d_in[14];
    const float* ln1g   = (const float*)d_in[15];
    const float* ln1b   = (const float*)d_in[16];
    const float* Wi     = (const float*)d_in[17];
    const float* bi     = (const float*)d_in[18];
    const float* Wo2    = (const float*)d_in[19];
    const float* bo2    = (const float*)d_in[20];
    const float* ln2g   = (const float*)d_in[21];
    const float* ln2b   = (const float*)d_in[22];
    const float* Wc     = (const float*)d_in[23];
    const float* bc     = (const float*)d_in[24];

    // workspace layout (all 16B-aligned), total 82.75 MB
    float*          ws    = (float*)d_ws;
    float*          h     = ws;                                      // 16.384 MB
    __hip_bfloat16* hbf   = (__hip_bfloat16*)(ws + 4096000);         //  8.192 MB
    __hip_bfloat16* ctxbf = (__hip_bfloat16*)(ws + 6144000);         //  8.192 MB
    __hip_bfloat16* wT    = (__hip_bfloat16*)(ws + 8192000);         //  0.787 MB
    float*          q     = ws + 8400000;                            // 16.384 MB
    float*          kk    = ws + 12496000;                           // 16.384 MB
    float*          vv    = ws + 16592000;                           // 16.384 MB
    __hip_bfloat16* hid   = (__hip_bfloat16*)q;   // aliases q+k (dead by FFN2)

    k_prep<<<dim3(64, 12), 256, 0, stream>>>(Wq, Wk, Wv, Wo, Wi, Wo2, wT);
    k_embed<<<MM / 16, 256, 0, stream>>>(x, W_in, b_in, pos, tt, lng, lnb, h, hbf);

    for (int l = 0; l < LL; ++l) {
        const __hip_bfloat16* wTq  = wT + l * 196608;
        const __hip_bfloat16* wTk  = wTq + 16384;
        const __hip_bfloat16* wTv  = wTq + 32768;
        const __hip_bfloat16* wTo  = wTq + 49152;
        const __hip_bfloat16* wTi  = wTq + 65536;
        const __hip_bfloat16* wTo2 = wTq + 131072;

        k_gemm_qkv<<<dim3(MM / 128, 3), 256, 0, stream>>>(
            hbf, wTq, wTk, wTv, bq + l * DD, bk + l * DD, bv + l * DD, q, kk, vv);

        k_attn<<<dim3(32, HH, BB), 256, 0, stream>>>(q, kk, vv, ctxbf);

        k_gemm_lnres<<<dim3(MM / 128, 1), 256, 0, stream>>>(
            ctxbf, DD, DD, wTo, bo + l * DD, h, ln1g + l * DD, ln1b + l * DD, h, hbf);

        k_gemm_gelu<<<dim3(MM / 128, 4), 256, 0, stream>>>(
            hbf, wTi, bi + l * FF, hid);

        k_gemm_lnres<<<dim3(MM / 128, 1), 256, 0, stream>>>(
            hid, FF, FF, wTo2, bo2 + l * DD, h, ln2g + l * DD, ln2b + l * DD, h, hbf);
    }

    k_final<<<BB, 128, 0, stream>>>(h, Wc, bc, (float*)d_out);
}